// Round 3
// baseline (1074.550 us; speedup 1.0000x reference)
//
#include <hip/hip_runtime.h>

// RecursiveLSTM: B=1024, T=96, H=50, num_pred=12.
// Round-3: back to lane-per-gate (block=256, 1 block = 1 sequence, 4 waves),
// which needs only 52 resident weight floats per lane. Round-0/1 failed
// because the scheduler hoist-clustered all 13 float4 h-loads, spiking peak
// pressure past the 128-VGPR cap of __launch_bounds__(256,4) -> the RA
// spilled the whole weight set (VGPR_Count 36/48) and re-loaded it every
// step. Fix: sched_barrier(0) fences every 3 ACC groups cap in-flight h
// values at 12 floats -> peak live ~85 VGPR, under the cap with margin.
// Round-2's wave-per-sequence (200 wt/lane) is abandoned: allocator held
// only 120 VGPRs and 1 wave/SIMD exposed all latency.

#define HSZ   50
#define G4    200      // 4*H gates
#define TLEN  96
#define MAXP  16       // >= num_pred

__global__ __launch_bounds__(256, 4)
void rec_lstm_kernel(const float* __restrict__ x,
                     const float* __restrict__ W_ih,
                     const float* __restrict__ W_hh,
                     const float* __restrict__ b_ih,
                     const float* __restrict__ b_hh,
                     const float* __restrict__ W_fc,
                     const float* __restrict__ b_fc,
                     const int*   __restrict__ num_pred,
                     float*       __restrict__ out)
{
    const int b   = blockIdx.x;
    const int tid = threadIdx.x;

    __shared__ float x_lds[TLEN];
    __shared__ float preds[MAXP];
    __shared__ __align__(16) float h_lds[52];   // padded to 13 float4
    __shared__ float gates[G4];

    // ---- one-time preload (uniform; clamp row for tid>=200) ----
    const int    gid = (tid < G4) ? tid : 0;
    const float* wr  = W_hh + gid * HSZ;

    // 13 named float4 registers holding this gate's W_hh row.
#define WLOAD(K) const float4 w##K = {wr[4*K+0], wr[4*K+1], wr[4*K+2], wr[4*K+3]};
    WLOAD(0) WLOAD(1) WLOAD(2) WLOAD(3) WLOAD(4) WLOAD(5)
    WLOAD(6) WLOAD(7) WLOAD(8) WLOAD(9) WLOAD(10) WLOAD(11)
    const float4 w12 = {wr[48], wr[49], 0.f, 0.f};
#undef WLOAD

    const float wih   = W_ih[gid];
    const float bsum  = b_ih[gid] + b_hh[gid];
    // unified activation: a = 1 - n/(exp(n*x)+1); n=1 -> sigmoid, n=2 -> tanh
    const float act_n = (tid >= 100 && tid < 150) ? 2.0f : 1.0f;

    const float wfc = (tid < HSZ) ? W_fc[tid] : 0.f;
    if (tid < TLEN) x_lds[tid] = x[b * TLEN + tid];
    if (tid == 0) { h_lds[50] = 0.f; h_lds[51] = 0.f; }
    const float bfc = b_fc[0];
    const int   NP  = num_pred[0];

    float c = 0.f;   // cell state, valid in threads < 50

    for (int p = 0; p < NP; ++p) {
        if (tid < HSZ) { c = 0.f; h_lds[tid] = 0.f; }
        __syncthreads();

        for (int t = 0; t < TLEN; ++t) {
            const int idx = p + t;                       // sliding window
            const float xv = (idx < TLEN) ? x_lds[idx] : preds[idx - TLEN];

            // ---- gate dot-product: 4 independent accumulator chains.
            // sched_barrier(0) every 3 groups: caps in-flight h values at
            // 12 floats so peak VGPR pressure stays well under the 128 cap
            // (the round-0/1 spill trigger was full 13-group load hoisting).
            float a0 = fmaf(wih, xv, bsum);
            float a1 = 0.f, a2 = 0.f, a3 = 0.f;
            const float4* h4 = (const float4*)h_lds;     // broadcast reads
#define ACC(K) { const float4 hv = h4[K];                              \
                 a0 = fmaf(w##K.x, hv.x, a0);                          \
                 a1 = fmaf(w##K.y, hv.y, a1);                          \
                 a2 = fmaf(w##K.z, hv.z, a2);                          \
                 a3 = fmaf(w##K.w, hv.w, a3); }
            ACC(0) ACC(1) ACC(2)
            __builtin_amdgcn_sched_barrier(0);
            ACC(3) ACC(4) ACC(5)
            __builtin_amdgcn_sched_barrier(0);
            ACC(6) ACC(7) ACC(8)
            __builtin_amdgcn_sched_barrier(0);
            ACC(9) ACC(10) ACC(11)
            __builtin_amdgcn_sched_barrier(0);
            ACC(12)
#undef ACC
            const float acc = (a0 + a1) + (a2 + a3);

            // branch-free activation (no dual transcendental path in the
            // waves that straddle the g-gate range)
            const float e = __expf(act_n * acc);
            const float a = 1.0f - act_n / (e + 1.0f);

            if (tid < G4) gates[tid] = a;
            __syncthreads();

            if (tid < HSZ) {
                const float gi = gates[tid];
                const float gf = gates[tid + 50];
                const float gg = gates[tid + 100];
                const float go = gates[tid + 150];
                c = fmaf(gf, c, gi * gg);
                // tanh(c) = 1 - 2/(exp(2c)+1), inf-safe
                h_lds[tid] = go * (1.0f - 2.0f / (__expf(2.0f * c) + 1.0f));
            }
            __syncthreads();
        }

        // ---- FC head: pred = h . W_fc + b_fc (wave-0 reduction) ----
        float v = (tid < HSZ) ? h_lds[tid] * wfc : 0.f;
        if (tid < 64) {
            #pragma unroll
            for (int off = 32; off >= 1; off >>= 1)
                v += __shfl_down(v, off, 64);
            if (tid == 0) {
                const float pr = v + bfc;
                preds[p] = pr;
                out[b * NP + p] = pr;
            }
        }
        __syncthreads();   // preds visible before next pass reads it
    }
}

extern "C" void kernel_launch(void* const* d_in, const int* in_sizes, int n_in,
                              void* d_out, int out_size, void* d_ws, size_t ws_size,
                              hipStream_t stream)
{
    const float* x    = (const float*)d_in[0];
    const float* W_ih = (const float*)d_in[1];
    const float* W_hh = (const float*)d_in[2];
    const float* b_ih = (const float*)d_in[3];
    const float* b_hh = (const float*)d_in[4];
    const float* W_fc = (const float*)d_in[5];
    const float* b_fc = (const float*)d_in[6];
    const int*   np   = (const int*)d_in[7];
    float* out = (float*)d_out;

    const int B = in_sizes[0] / TLEN;   // 1024
    rec_lstm_kernel<<<B, 256, 0, stream>>>(x, W_ih, W_hh, b_ih, b_hh,
                                           W_fc, b_fc, np, out);
}

// Round 4
// 1004.034 us; speedup vs baseline: 1.0702x; 1.0702x over previous
//
#include <hip/hip_runtime.h>

// RecursiveLSTM: B=1024 sequences, T=96, H=50, num_pred=12.
// WAVE-PER-SEQUENCE (1024 blocks x 64 threads). Lane j<50 owns hidden unit
// j: computes its 4 gates (4 indep FMA chains over h), then c_j, h_j
// in-thread. Cross-lane traffic per step: 13 ds_read_b128 h-broadcasts +
// 1 ds_write_b32. One barrier per step.
//
// THE FIX THIS ROUND: rounds 0-3 all failed the same way — the W_hh loads
// are invariant loads from __restrict__ const pointers, which LLVM treats
// as trivially REMATERIALIZABLE, so the RA re-loads them inside the loop
// at ANY register budget (VGPR stuck at 36/48/60/120, ~3x issue bloat).
// Empty `asm volatile("" : "+v"(x))` pins make each weight the result of
// an opaque asm op: not rematerializable, must stay live. Zero instructions
// emitted. Budget 512 VGPR under __launch_bounds__(64,1); ~260 live.
// FALSIFIER: VGPR_Count must come back ~240-260, else the pin failed.

#define HSZ   50
#define TLEN  96
#define MAXP  16

__global__ __launch_bounds__(64, 1)
void rec_lstm_kernel(const float* __restrict__ x,
                     const float* __restrict__ W_ih,
                     const float* __restrict__ W_hh,
                     const float* __restrict__ b_ih,
                     const float* __restrict__ b_hh,
                     const float* __restrict__ W_fc,
                     const float* __restrict__ b_fc,
                     const int*   __restrict__ num_pred,
                     float*       __restrict__ out)
{
    const int b = blockIdx.x;
    const int j = threadIdx.x;            // hidden-unit index; active j<50
    const int u = (j < HSZ) ? j : 0;      // clamped row for idle lanes

    __shared__ float x_lds[TLEN];
    __shared__ float preds[MAXP];
    __shared__ __align__(16) float h_lds[52];   // padded to 13 float4

    // ---- one-time preload: W_hh rows for the 4 gates of unit u ----
    const float* ri = W_hh + (u +   0) * HSZ;
    const float* rf = W_hh + (u +  50) * HSZ;
    const float* rg = W_hh + (u + 100) * HSZ;
    const float* ro = W_hh + (u + 150) * HSZ;

#define LD4(P,K)  {(P)[4*(K)], (P)[4*(K)+1], (P)[4*(K)+2], (P)[4*(K)+3]}
#define LDROW(N,P) \
    float4 N##0=LD4(P,0),  N##1=LD4(P,1),  N##2=LD4(P,2),  N##3=LD4(P,3),  \
           N##4=LD4(P,4),  N##5=LD4(P,5),  N##6=LD4(P,6),  N##7=LD4(P,7),  \
           N##8=LD4(P,8),  N##9=LD4(P,9),  N##10=LD4(P,10), N##11=LD4(P,11); \
    float4 N##12 = {(P)[48], (P)[49], 0.f, 0.f};
    LDROW(wi, ri)
    LDROW(wf, rf)
    LDROW(wg, rg)
    LDROW(wo, ro)
#undef LDROW
#undef LD4

    float xii = W_ih[u], xif = W_ih[u+50], xig = W_ih[u+100], xio = W_ih[u+150];
    float bi = b_ih[u]     + b_hh[u];
    float bf = b_ih[u+50]  + b_hh[u+50];
    float bg = b_ih[u+100] + b_hh[u+100];
    float bo = b_ih[u+150] + b_hh[u+150];

    // ---- PIN: make every weight non-rematerializable (no code emitted) ----
#define PIN4(V) asm volatile("" : "+v"(V.x), "+v"(V.y), "+v"(V.z), "+v"(V.w));
#define PINROW(N) PIN4(N##0) PIN4(N##1) PIN4(N##2) PIN4(N##3) PIN4(N##4) \
                  PIN4(N##5) PIN4(N##6) PIN4(N##7) PIN4(N##8) PIN4(N##9) \
                  PIN4(N##10) PIN4(N##11) PIN4(N##12)
    PINROW(wi) PINROW(wf) PINROW(wg) PINROW(wo)
#undef PINROW
#undef PIN4
    asm volatile("" : "+v"(xii), "+v"(xif), "+v"(xig), "+v"(xio),
                      "+v"(bi),  "+v"(bf),  "+v"(bg),  "+v"(bo));

    const float wfc = (j < HSZ) ? W_fc[j] : 0.f;
    const float bfc = b_fc[0];
    const int   NP  = num_pred[0];

    if (j < 48) { x_lds[j] = x[b*TLEN + j]; x_lds[j+48] = x[b*TLEN + j + 48]; }
    if (j == 0) { h_lds[50] = 0.f; h_lds[51] = 0.f; }

    float c = 0.f;   // cell state of unit j

    for (int p = 0; p < NP; ++p) {
        if (j < HSZ) { c = 0.f; h_lds[j] = 0.f; }
        __syncthreads();

        float hn = 0.f;   // h_j, kept in-register for the FC head

        for (int t = 0; t < TLEN; ++t) {
            const int idx = p + t;                        // sliding window
            const float xv = (idx < TLEN) ? x_lds[idx] : preds[idx - TLEN];

            // ---- 4 gate dot-products, 4 independent FMA chains ----
            float ai = fmaf(xii, xv, bi);
            float af = fmaf(xif, xv, bf);
            float ag = fmaf(xig, xv, bg);
            float ao = fmaf(xio, xv, bo);
            const float4* h4 = (const float4*)h_lds;      // broadcast reads
#define ACC(K) { const float4 hv = h4[K];                                  \
    ai = fmaf(wi##K.x, hv.x, ai); af = fmaf(wf##K.x, hv.x, af);            \
    ag = fmaf(wg##K.x, hv.x, ag); ao = fmaf(wo##K.x, hv.x, ao);            \
    ai = fmaf(wi##K.y, hv.y, ai); af = fmaf(wf##K.y, hv.y, af);            \
    ag = fmaf(wg##K.y, hv.y, ag); ao = fmaf(wo##K.y, hv.y, ao);            \
    ai = fmaf(wi##K.z, hv.z, ai); af = fmaf(wf##K.z, hv.z, af);            \
    ag = fmaf(wg##K.z, hv.z, ag); ao = fmaf(wo##K.z, hv.z, ao);            \
    ai = fmaf(wi##K.w, hv.w, ai); af = fmaf(wf##K.w, hv.w, af);            \
    ag = fmaf(wg##K.w, hv.w, ag); ao = fmaf(wo##K.w, hv.w, ao); }
            ACC(0) ACC(1) ACC(2) ACC(3) ACC(4) ACC(5) ACC(6)
            ACC(7) ACC(8) ACC(9) ACC(10) ACC(11) ACC(12)
#undef ACC

            // activations: sigmoid(i,f,o), tanh(g); inf-safe forms
            const float gi = 1.0f / (1.0f + __expf(-ai));
            const float gf = 1.0f / (1.0f + __expf(-af));
            const float gg = 1.0f - 2.0f / (__expf(2.0f * ag) + 1.0f);
            const float go = 1.0f / (1.0f + __expf(-ao));

            c  = fmaf(gf, c, gi * gg);
            hn = go * (1.0f - 2.0f / (__expf(2.0f * c) + 1.0f));

            if (j < HSZ) h_lds[j] = hn;
            __syncthreads();   // single wave: orders ds_write -> broadcasts
        }

        // ---- FC head: pred = h . W_fc + b_fc (full-wave shuffle reduce) ----
        float v = (j < HSZ) ? hn * wfc : 0.f;
        #pragma unroll
        for (int off = 32; off >= 1; off >>= 1)
            v += __shfl_down(v, off, 64);
        if (j == 0) {
            const float pr = v + bfc;
            preds[p] = pr;
            out[b * NP + p] = pr;
        }
        __syncthreads();   // preds visible before next pass reads it
    }
}

extern "C" void kernel_launch(void* const* d_in, const int* in_sizes, int n_in,
                              void* d_out, int out_size, void* d_ws, size_t ws_size,
                              hipStream_t stream)
{
    const float* x    = (const float*)d_in[0];
    const float* W_ih = (const float*)d_in[1];
    const float* W_hh = (const float*)d_in[2];
    const float* b_ih = (const float*)d_in[3];
    const float* b_hh = (const float*)d_in[4];
    const float* W_fc = (const float*)d_in[5];
    const float* b_fc = (const float*)d_in[6];
    const int*   np   = (const int*)d_in[7];
    float* out = (float*)d_out;

    const int B = in_sizes[0] / TLEN;   // 1024
    rec_lstm_kernel<<<B, 64, 0, stream>>>(x, W_ih, W_hh, b_ih, b_hh,
                                          W_fc, b_fc, np, out);
}

// Round 7
// 964.392 us; speedup vs baseline: 1.1142x; 1.0411x over previous
//
#include <hip/hip_runtime.h>

// RecursiveLSTM: B=1024 sequences, T=96, H=50, num_pred=12.
// WAVE-PER-SEQUENCE (1024 blocks x 64 threads = exactly 1 wave per SIMD).
// Lane j<50 owns hidden unit j: its 4 gate dot-products over h, then c_j,
// h_j in-thread. Per-step traffic: 13 ds_read_b128 h-broadcasts + 1
// ds_write_b32 + 1 single-wave barrier.
//
// ROUND 7 = ROUND 6 RERUN (round-6 bench was an infra failure: "container
// failed twice", no compile error, no counters; the kernel never ran).
//
// DIAGNOSIS (rounds 0-5): the RA was holding the 200 weight floats in
// AGPRs (CDNA spill-to-AGPR), paying ~400 v_accvgpr_read VALU copies per
// step -- VALUBusy high, FETCH flat, arch VGPR frozen at ~120. gfx950
// VALU cannot source AGPRs (round-5 assembler error proved this), so the
// copies are unavoidable *unless the scheduler's occupancy target is
// pinned to 1 wave/EU*, raising the arch-VGPR pressure ceiling to the
// full 512-reg file. That knob is amdgpu_waves_per_eu(1,1) --
// __launch_bounds__(64,1) did NOT do it (scheduler still targeted ~4
// waves -> ~128-reg ceiling).
// FALSIFIER: VGPR_Count must jump to ~260-320; if it stays ~120 the
// theory is wrong and round 8 moves weights to LDS streaming.

#define HSZ   50
#define TLEN  96
#define MAXP  16

__global__ __attribute__((amdgpu_flat_work_group_size(64, 64),
                          amdgpu_waves_per_eu(1, 1)))
void rec_lstm_kernel(const float* __restrict__ x,
                     const float* __restrict__ W_ih,
                     const float* __restrict__ W_hh,
                     const float* __restrict__ b_ih,
                     const float* __restrict__ b_hh,
                     const float* __restrict__ W_fc,
                     const float* __restrict__ b_fc,
                     const int*   __restrict__ num_pred,
                     float*       __restrict__ out)
{
    const int b = blockIdx.x;
    const int j = threadIdx.x;            // hidden-unit index; active j<50
    const int u = (j < HSZ) ? j : 0;      // clamped row for idle lanes

    __shared__ float xbuf[TLEN + MAXP];   // x followed by appended preds
    __shared__ __align__(16) float h_lds[52];   // padded to 13 float4

    // ---- one-time preload: W_hh rows for the 4 gates of unit u ----
    const float* ri = W_hh + (u +   0) * HSZ;
    const float* rf = W_hh + (u +  50) * HSZ;
    const float* rg = W_hh + (u + 100) * HSZ;
    const float* ro = W_hh + (u + 150) * HSZ;

#define LD4(P,K)  {(P)[4*(K)], (P)[4*(K)+1], (P)[4*(K)+2], (P)[4*(K)+3]}
#define LDROW(N,P) \
    float4 N##0=LD4(P,0),  N##1=LD4(P,1),  N##2=LD4(P,2),  N##3=LD4(P,3),  \
           N##4=LD4(P,4),  N##5=LD4(P,5),  N##6=LD4(P,6),  N##7=LD4(P,7),  \
           N##8=LD4(P,8),  N##9=LD4(P,9),  N##10=LD4(P,10), N##11=LD4(P,11); \
    float4 N##12 = {(P)[48], (P)[49], 0.f, 0.f};
    LDROW(wi, ri)
    LDROW(wf, rf)
    LDROW(wg, rg)
    LDROW(wo, ro)
#undef LDROW
#undef LD4

    float xii = W_ih[u], xif = W_ih[u+50], xig = W_ih[u+100], xio = W_ih[u+150];
    float bi = b_ih[u]     + b_hh[u];
    float bf = b_ih[u+50]  + b_hh[u+50];
    float bg = b_ih[u+100] + b_hh[u+100];
    float bo = b_ih[u+150] + b_hh[u+150];

    // ---- anti-remat pins (no code emitted) ----
#define PIN4(V) asm("" : "+v"(V.x), "+v"(V.y), "+v"(V.z), "+v"(V.w));
#define PINROW(N) PIN4(N##0) PIN4(N##1) PIN4(N##2) PIN4(N##3) PIN4(N##4) \
                  PIN4(N##5) PIN4(N##6) PIN4(N##7) PIN4(N##8) PIN4(N##9) \
                  PIN4(N##10) PIN4(N##11) PIN4(N##12)
    PINROW(wi) PINROW(wf) PINROW(wg) PINROW(wo)
#undef PINROW
#undef PIN4
    asm("" : "+v"(xii), "+v"(xif), "+v"(xig), "+v"(xio),
             "+v"(bi),  "+v"(bf),  "+v"(bg),  "+v"(bo));

    const float wfc = (j < HSZ) ? W_fc[j] : 0.f;
    const float bfc = b_fc[0];
    const int   NP  = num_pred[0];

    if (j < 48) { xbuf[j] = x[b*TLEN + j]; xbuf[j+48] = x[b*TLEN + j + 48]; }
    if (j == 0) { h_lds[50] = 0.f; h_lds[51] = 0.f; }

    float c = 0.f;   // cell state of unit j

    for (int p = 0; p < NP; ++p) {
        if (j < HSZ) { c = 0.f; h_lds[j] = 0.f; }
        __syncthreads();

        float hn = 0.f;   // h_j, stays in-register for the FC head

        #pragma unroll 1
        for (int t = 0; t < TLEN; ++t) {
            const float xv = xbuf[p + t];                 // broadcast read

            // ---- 4 gate dot-products, 4 independent FMA chains ----
            float ai = fmaf(xii, xv, bi);
            float af = fmaf(xif, xv, bf);
            float ag = fmaf(xig, xv, bg);
            float ao = fmaf(xio, xv, bo);
            const float4* h4 = (const float4*)h_lds;      // broadcast reads
#define ACC(K) { const float4 hv = h4[K];                                  \
    ai = fmaf(wi##K.x, hv.x, ai); af = fmaf(wf##K.x, hv.x, af);            \
    ag = fmaf(wg##K.x, hv.x, ag); ao = fmaf(wo##K.x, hv.x, ao);            \
    ai = fmaf(wi##K.y, hv.y, ai); af = fmaf(wf##K.y, hv.y, af);            \
    ag = fmaf(wg##K.y, hv.y, ag); ao = fmaf(wo##K.y, hv.y, ao);            \
    ai = fmaf(wi##K.z, hv.z, ai); af = fmaf(wf##K.z, hv.z, af);            \
    ag = fmaf(wg##K.z, hv.z, ag); ao = fmaf(wo##K.z, hv.z, ao);            \
    ai = fmaf(wi##K.w, hv.w, ai); af = fmaf(wf##K.w, hv.w, af);            \
    ag = fmaf(wg##K.w, hv.w, ag); ao = fmaf(wo##K.w, hv.w, ao); }
            ACC(0) ACC(1) ACC(2) ACC(3) ACC(4) ACC(5) ACC(6)
            ACC(7) ACC(8) ACC(9) ACC(10) ACC(11) ACC(12)
#undef ACC

            // activations: sigmoid(i,f,o), tanh(g); inf-safe; 1-ulp rcp
            const float gi = __builtin_amdgcn_rcpf(1.0f + __expf(-ai));
            const float gf = __builtin_amdgcn_rcpf(1.0f + __expf(-af));
            const float gg = 1.0f - 2.0f * __builtin_amdgcn_rcpf(__expf(2.0f*ag) + 1.0f);
            const float go = __builtin_amdgcn_rcpf(1.0f + __expf(-ao));

            c  = fmaf(gf, c, gi * gg);
            hn = go * (1.0f - 2.0f * __builtin_amdgcn_rcpf(__expf(2.0f*c) + 1.0f));

            if (j < HSZ) h_lds[j] = hn;
            __syncthreads();   // single-wave: orders ds_write -> broadcasts
        }

        // ---- FC head: pred = h . W_fc + b_fc (full-wave shuffle reduce) ----
        float v = (j < HSZ) ? hn * wfc : 0.f;
        #pragma unroll
        for (int off = 32; off >= 1; off >>= 1)
            v += __shfl_down(v, off, 64);
        if (j == 0) {
            const float pr = v + bfc;
            xbuf[TLEN + p] = pr;               // becomes next input
            out[b * NP + p] = pr;
        }
        __syncthreads();
    }
}

extern "C" void kernel_launch(void* const* d_in, const int* in_sizes, int n_in,
                              void* d_out, int out_size, void* d_ws, size_t ws_size,
                              hipStream_t stream)
{
    const float* x    = (const float*)d_in[0];
    const float* W_ih = (const float*)d_in[1];
    const float* W_hh = (const float*)d_in[2];
    const float* b_ih = (const float*)d_in[3];
    const float* b_hh = (const float*)d_in[4];
    const float* W_fc = (const float*)d_in[5];
    const float* b_fc = (const float*)d_in[6];
    const int*   np   = (const int*)d_in[7];
    float* out = (float*)d_out;

    const int B = in_sizes[0] / TLEN;   // 1024
    rec_lstm_kernel<<<B, 64, 0, stream>>>(x, W_ih, W_hh, b_ih, b_hh,
                                          W_fc, b_fc, np, out);
}

// Round 8
// 538.056 us; speedup vs baseline: 1.9971x; 1.7924x over previous
//
#include <hip/hip_runtime.h>
#include <stdint.h>

// RecursiveLSTM: B=1024 sequences, T=96, H=50, num_pred=12.
// WAVE-PER-SEQUENCE (1024 blocks x 64 threads). Lane j<50 owns hidden unit
// j; computes its 4 gates + c_j,h_j in-thread. h broadcast via LDS.
//
// ROUND-8: the entire 96-step t-loop lives in ONE inline-asm block with the
// 200 W_hh weights in FIXED registers v[40:239], loaded inside the asm
// (12x per kernel, L1-hot). Rationale: rounds 0-7 proved the register
// allocator ALWAYS parks the weights in AGPRs (arch VGPR frozen ~120-132 at
// every launch-bound regime) and gfx950 VALU cannot source AGPRs (round-5
// assembler error), so every weight use paid a v_accvgpr_read copy
// (~200 extra VALU/step = the whole 2-3x gap). Hand-managed fixed regs
// are the only copy-free, BW-free weight store.
// Gate math: v_pk_fma_f32 (packed f32) -> 100 FMA-issues instead of 200.
// Activations: exp2-based sigmoid/tanh + v_rcp (same numerics as the
// passing round-4/7 kernels, absmax 4.9e-4).

#define HSZ   50
#define TLEN  96
#define MAXP  16

__global__ __attribute__((amdgpu_flat_work_group_size(64, 64),
                          amdgpu_waves_per_eu(1, 1)))
void rec_lstm_kernel(const float* __restrict__ x,
                     const float* __restrict__ W_ih,
                     const float* __restrict__ W_hh,
                     const float* __restrict__ b_ih,
                     const float* __restrict__ b_hh,
                     const float* __restrict__ W_fc,
                     const float* __restrict__ b_fc,
                     const int*   __restrict__ num_pred,
                     float*       __restrict__ out)
{
    const int b = blockIdx.x;
    const int j = threadIdx.x;            // hidden-unit index; active j<50
    const int u = (j < HSZ) ? j : 0;      // clamped row for idle lanes

    __shared__ float xbuf[TLEN + MAXP];         // x ++ appended preds
    __shared__ __align__(16) float h_lds[64];   // slots 50..63 = garbage pad

    // LDS byte offsets (shared aperture is 4GB-aligned: low 32 bits of the
    // generic address ARE the LDS offset)
    const uint32_t xbuf_off = (uint32_t)(uintptr_t)&xbuf[0];
    const uint32_t hb_off   = (uint32_t)(uintptr_t)&h_lds[0];
    const uint32_t hw_off   = hb_off + 4u * (uint32_t)j;

    // per-gate-row byte offsets into W_hh (rows u, u+50, u+100, u+150)
    const uint32_t woi = (uint32_t)(u        ) * 200u;
    const uint32_t wof = (uint32_t)(u +  50  ) * 200u;
    const uint32_t wog = (uint32_t)(u + 100  ) * 200u;
    const uint32_t woo = (uint32_t)(u + 150  ) * 200u;

    const float xii = W_ih[u], xif = W_ih[u+50], xig = W_ih[u+100], xio = W_ih[u+150];
    const float bi = b_ih[u]     + b_hh[u];
    const float bf = b_ih[u+50]  + b_hh[u+50];
    const float bg = b_ih[u+100] + b_hh[u+100];
    const float bo = b_ih[u+150] + b_hh[u+150];
    const float wfc = (j < HSZ) ? W_fc[j] : 0.f;
    const float bfc = b_fc[0];
    const int   NP  = num_pred[0];

    if (j < 48) { xbuf[j] = x[b*TLEN + j]; xbuf[j+48] = x[b*TLEN + j + 48]; }

    for (int p = 0; p < NP; ++p) {
        float hn;
        const uint32_t xa0 = xbuf_off + 4u * (uint32_t)p;

        asm volatile(
            // ---- prologue: addresses, zero h, zero c ----
            "v_mov_b32 v32, %[xa0]\n\t"
            "v_mov_b32 v33, %[hb]\n\t"
            "v_mov_b32 v34, %[hw]\n\t"
            "v_mov_b32 v29, 0\n\t"
            "ds_write_b32 v34, v29\n\t"
            "v_mov_b32 v30, 0\n\t"                 // c = 0
            // ---- load W_hh rows into fixed regs (i:40-89 f:90-139 g:140-189 o:190-239)
            "global_load_dwordx4 v[40:43],  %[woi], %[wb]\n\t"
            "global_load_dwordx4 v[44:47],  %[woi], %[wb] offset:16\n\t"
            "global_load_dwordx4 v[48:51],  %[woi], %[wb] offset:32\n\t"
            "global_load_dwordx4 v[52:55],  %[woi], %[wb] offset:48\n\t"
            "global_load_dwordx4 v[56:59],  %[woi], %[wb] offset:64\n\t"
            "global_load_dwordx4 v[60:63],  %[woi], %[wb] offset:80\n\t"
            "global_load_dwordx4 v[64:67],  %[woi], %[wb] offset:96\n\t"
            "global_load_dwordx4 v[68:71],  %[woi], %[wb] offset:112\n\t"
            "global_load_dwordx4 v[72:75],  %[woi], %[wb] offset:128\n\t"
            "global_load_dwordx4 v[76:79],  %[woi], %[wb] offset:144\n\t"
            "global_load_dwordx4 v[80:83],  %[woi], %[wb] offset:160\n\t"
            "global_load_dwordx4 v[84:87],  %[woi], %[wb] offset:176\n\t"
            "global_load_dwordx2 v[88:89],  %[woi], %[wb] offset:192\n\t"
            "global_load_dwordx4 v[90:93],  %[wof], %[wb]\n\t"
            "global_load_dwordx4 v[94:97],  %[wof], %[wb] offset:16\n\t"
            "global_load_dwordx4 v[98:101], %[wof], %[wb] offset:32\n\t"
            "global_load_dwordx4 v[102:105],%[wof], %[wb] offset:48\n\t"
            "global_load_dwordx4 v[106:109],%[wof], %[wb] offset:64\n\t"
            "global_load_dwordx4 v[110:113],%[wof], %[wb] offset:80\n\t"
            "global_load_dwordx4 v[114:117],%[wof], %[wb] offset:96\n\t"
            "global_load_dwordx4 v[118:121],%[wof], %[wb] offset:112\n\t"
            "global_load_dwordx4 v[122:125],%[wof], %[wb] offset:128\n\t"
            "global_load_dwordx4 v[126:129],%[wof], %[wb] offset:144\n\t"
            "global_load_dwordx4 v[130:133],%[wof], %[wb] offset:160\n\t"
            "global_load_dwordx4 v[134:137],%[wof], %[wb] offset:176\n\t"
            "global_load_dwordx2 v[138:139],%[wof], %[wb] offset:192\n\t"
            "global_load_dwordx4 v[140:143],%[wog], %[wb]\n\t"
            "global_load_dwordx4 v[144:147],%[wog], %[wb] offset:16\n\t"
            "global_load_dwordx4 v[148:151],%[wog], %[wb] offset:32\n\t"
            "global_load_dwordx4 v[152:155],%[wog], %[wb] offset:48\n\t"
            "global_load_dwordx4 v[156:159],%[wog], %[wb] offset:64\n\t"
            "global_load_dwordx4 v[160:163],%[wog], %[wb] offset:80\n\t"
            "global_load_dwordx4 v[164:167],%[wog], %[wb] offset:96\n\t"
            "global_load_dwordx4 v[168:171],%[wog], %[wb] offset:112\n\t"
            "global_load_dwordx4 v[172:175],%[wog], %[wb] offset:128\n\t"
            "global_load_dwordx4 v[176:179],%[wog], %[wb] offset:144\n\t"
            "global_load_dwordx4 v[180:183],%[wog], %[wb] offset:160\n\t"
            "global_load_dwordx4 v[184:187],%[wog], %[wb] offset:176\n\t"
            "global_load_dwordx2 v[188:189],%[wog], %[wb] offset:192\n\t"
            "global_load_dwordx4 v[190:193],%[woo], %[wb]\n\t"
            "global_load_dwordx4 v[194:197],%[woo], %[wb] offset:16\n\t"
            "global_load_dwordx4 v[198:201],%[woo], %[wb] offset:32\n\t"
            "global_load_dwordx4 v[202:205],%[woo], %[wb] offset:48\n\t"
            "global_load_dwordx4 v[206:209],%[woo], %[wb] offset:64\n\t"
            "global_load_dwordx4 v[210:213],%[woo], %[wb] offset:80\n\t"
            "global_load_dwordx4 v[214:217],%[woo], %[wb] offset:96\n\t"
            "global_load_dwordx4 v[218:221],%[woo], %[wb] offset:112\n\t"
            "global_load_dwordx4 v[222:225],%[woo], %[wb] offset:128\n\t"
            "global_load_dwordx4 v[226:229],%[woo], %[wb] offset:144\n\t"
            "global_load_dwordx4 v[230:233],%[woo], %[wb] offset:160\n\t"
            "global_load_dwordx4 v[234:237],%[woo], %[wb] offset:176\n\t"
            "global_load_dwordx2 v[238:239],%[woo], %[wb] offset:192\n\t"
            "s_waitcnt vmcnt(0) lgkmcnt(0)\n\t"
            "s_mov_b32 s20, 96\n\t"
            // ================= t-loop =================
            "1:\n\t"
            "ds_read_b32 v28, v32\n\t"                 // xv
            "ds_read_b128 v[4:7], v33\n\t"             // h[0:3]
            "ds_read_b128 v[16:19], v33 offset:16\n\t" // h[4:7]
            "v_add_u32 v32, 4, v32\n\t"
            "s_waitcnt lgkmcnt(2)\n\t"
            "v_fma_f32 v8,  %[xwi], v28, %[bi]\n\t"
            "v_mov_b32 v9, 0\n\t"
            "v_fma_f32 v10, %[xwf], v28, %[bf]\n\t"
            "v_mov_b32 v11, 0\n\t"
            "v_fma_f32 v12, %[xwg], v28, %[bg]\n\t"
            "v_mov_b32 v13, 0\n\t"
            "v_fma_f32 v14, %[xwo], v28, %[bo]\n\t"
            "v_mov_b32 v15, 0\n\t"
            // m=0 (A): kp 0,1
            "s_waitcnt lgkmcnt(1)\n\t"
            "v_pk_fma_f32 v[8:9],   v[40:41],   v[4:5], v[8:9]\n\t"
            "v_pk_fma_f32 v[10:11], v[90:91],   v[4:5], v[10:11]\n\t"
            "v_pk_fma_f32 v[12:13], v[140:141], v[4:5], v[12:13]\n\t"
            "v_pk_fma_f32 v[14:15], v[190:191], v[4:5], v[14:15]\n\t"
            "v_pk_fma_f32 v[8:9],   v[42:43],   v[6:7], v[8:9]\n\t"
            "v_pk_fma_f32 v[10:11], v[92:93],   v[6:7], v[10:11]\n\t"
            "v_pk_fma_f32 v[12:13], v[142:143], v[6:7], v[12:13]\n\t"
            "v_pk_fma_f32 v[14:15], v[192:193], v[6:7], v[14:15]\n\t"
            "ds_read_b128 v[4:7], v33 offset:32\n\t"
            // m=1 (B): kp 2,3
            "s_waitcnt lgkmcnt(1)\n\t"
            "v_pk_fma_f32 v[8:9],   v[44:45],   v[16:17], v[8:9]\n\t"
            "v_pk_fma_f32 v[10:11], v[94:95],   v[16:17], v[10:11]\n\t"
            "v_pk_fma_f32 v[12:13], v[144:145], v[16:17], v[12:13]\n\t"
            "v_pk_fma_f32 v[14:15], v[194:195], v[16:17], v[14:15]\n\t"
            "v_pk_fma_f32 v[8:9],   v[46:47],   v[18:19], v[8:9]\n\t"
            "v_pk_fma_f32 v[10:11], v[96:97],   v[18:19], v[10:11]\n\t"
            "v_pk_fma_f32 v[12:13], v[146:147], v[18:19], v[12:13]\n\t"
            "v_pk_fma_f32 v[14:15], v[196:197], v[18:19], v[14:15]\n\t"
            "ds_read_b128 v[16:19], v33 offset:48\n\t"
            // m=2 (A): kp 4,5
            "s_waitcnt lgkmcnt(1)\n\t"
            "v_pk_fma_f32 v[8:9],   v[48:49],   v[4:5], v[8:9]\n\t"
            "v_pk_fma_f32 v[10:11], v[98:99],   v[4:5], v[10:11]\n\t"
            "v_pk_fma_f32 v[12:13], v[148:149], v[4:5], v[12:13]\n\t"
            "v_pk_fma_f32 v[14:15], v[198:199], v[4:5], v[14:15]\n\t"
            "v_pk_fma_f32 v[8:9],   v[50:51],   v[6:7], v[8:9]\n\t"
            "v_pk_fma_f32 v[10:11], v[100:101], v[6:7], v[10:11]\n\t"
            "v_pk_fma_f32 v[12:13], v[150:151], v[6:7], v[12:13]\n\t"
            "v_pk_fma_f32 v[14:15], v[200:201], v[6:7], v[14:15]\n\t"
            "ds_read_b128 v[4:7], v33 offset:64\n\t"
            // m=3 (B): kp 6,7
            "s_waitcnt lgkmcnt(1)\n\t"
            "v_pk_fma_f32 v[8:9],   v[52:53],   v[16:17], v[8:9]\n\t"
            "v_pk_fma_f32 v[10:11], v[102:103], v[16:17], v[10:11]\n\t"
            "v_pk_fma_f32 v[12:13], v[152:153], v[16:17], v[12:13]\n\t"
            "v_pk_fma_f32 v[14:15], v[202:203], v[16:17], v[14:15]\n\t"
            "v_pk_fma_f32 v[8:9],   v[54:55],   v[18:19], v[8:9]\n\t"
            "v_pk_fma_f32 v[10:11], v[104:105], v[18:19], v[10:11]\n\t"
            "v_pk_fma_f32 v[12:13], v[154:155], v[18:19], v[12:13]\n\t"
            "v_pk_fma_f32 v[14:15], v[204:205], v[18:19], v[14:15]\n\t"
            "ds_read_b128 v[16:19], v33 offset:80\n\t"
            // m=4 (A): kp 8,9
            "s_waitcnt lgkmcnt(1)\n\t"
            "v_pk_fma_f32 v[8:9],   v[56:57],   v[4:5], v[8:9]\n\t"
            "v_pk_fma_f32 v[10:11], v[106:107], v[4:5], v[10:11]\n\t"
            "v_pk_fma_f32 v[12:13], v[156:157], v[4:5], v[12:13]\n\t"
            "v_pk_fma_f32 v[14:15], v[206:207], v[4:5], v[14:15]\n\t"
            "v_pk_fma_f32 v[8:9],   v[58:59],   v[6:7], v[8:9]\n\t"
            "v_pk_fma_f32 v[10:11], v[108:109], v[6:7], v[10:11]\n\t"
            "v_pk_fma_f32 v[12:13], v[158:159], v[6:7], v[12:13]\n\t"
            "v_pk_fma_f32 v[14:15], v[208:209], v[6:7], v[14:15]\n\t"
            "ds_read_b128 v[4:7], v33 offset:96\n\t"
            // m=5 (B): kp 10,11
            "s_waitcnt lgkmcnt(1)\n\t"
            "v_pk_fma_f32 v[8:9],   v[60:61],   v[16:17], v[8:9]\n\t"
            "v_pk_fma_f32 v[10:11], v[110:111], v[16:17], v[10:11]\n\t"
            "v_pk_fma_f32 v[12:13], v[160:161], v[16:17], v[12:13]\n\t"
            "v_pk_fma_f32 v[14:15], v[210:211], v[16:17], v[14:15]\n\t"
            "v_pk_fma_f32 v[8:9],   v[62:63],   v[18:19], v[8:9]\n\t"
            "v_pk_fma_f32 v[10:11], v[112:113], v[18:19], v[10:11]\n\t"
            "v_pk_fma_f32 v[12:13], v[162:163], v[18:19], v[12:13]\n\t"
            "v_pk_fma_f32 v[14:15], v[212:213], v[18:19], v[14:15]\n\t"
            "ds_read_b128 v[16:19], v33 offset:112\n\t"
            // m=6 (A): kp 12,13
            "s_waitcnt lgkmcnt(1)\n\t"
            "v_pk_fma_f32 v[8:9],   v[64:65],   v[4:5], v[8:9]\n\t"
            "v_pk_fma_f32 v[10:11], v[114:115], v[4:5], v[10:11]\n\t"
            "v_pk_fma_f32 v[12:13], v[164:165], v[4:5], v[12:13]\n\t"
            "v_pk_fma_f32 v[14:15], v[214:215], v[4:5], v[14:15]\n\t"
            "v_pk_fma_f32 v[8:9],   v[66:67],   v[6:7], v[8:9]\n\t"
            "v_pk_fma_f32 v[10:11], v[116:117], v[6:7], v[10:11]\n\t"
            "v_pk_fma_f32 v[12:13], v[166:167], v[6:7], v[12:13]\n\t"
            "v_pk_fma_f32 v[14:15], v[216:217], v[6:7], v[14:15]\n\t"
            "ds_read_b128 v[4:7], v33 offset:128\n\t"
            // m=7 (B): kp 14,15
            "s_waitcnt lgkmcnt(1)\n\t"
            "v_pk_fma_f32 v[8:9],   v[68:69],   v[16:17], v[8:9]\n\t"
            "v_pk_fma_f32 v[10:11], v[118:119], v[16:17], v[10:11]\n\t"
            "v_pk_fma_f32 v[12:13], v[168:169], v[16:17], v[12:13]\n\t"
            "v_pk_fma_f32 v[14:15], v[218:219], v[16:17], v[14:15]\n\t"
            "v_pk_fma_f32 v[8:9],   v[70:71],   v[18:19], v[8:9]\n\t"
            "v_pk_fma_f32 v[10:11], v[120:121], v[18:19], v[10:11]\n\t"
            "v_pk_fma_f32 v[12:13], v[170:171], v[18:19], v[12:13]\n\t"
            "v_pk_fma_f32 v[14:15], v[220:221], v[18:19], v[14:15]\n\t"
            "ds_read_b128 v[16:19], v33 offset:144\n\t"
            // m=8 (A): kp 16,17
            "s_waitcnt lgkmcnt(1)\n\t"
            "v_pk_fma_f32 v[8:9],   v[72:73],   v[4:5], v[8:9]\n\t"
            "v_pk_fma_f32 v[10:11], v[122:123], v[4:5], v[10:11]\n\t"
            "v_pk_fma_f32 v[12:13], v[172:173], v[4:5], v[12:13]\n\t"
            "v_pk_fma_f32 v[14:15], v[222:223], v[4:5], v[14:15]\n\t"
            "v_pk_fma_f32 v[8:9],   v[74:75],   v[6:7], v[8:9]\n\t"
            "v_pk_fma_f32 v[10:11], v[124:125], v[6:7], v[10:11]\n\t"
            "v_pk_fma_f32 v[12:13], v[174:175], v[6:7], v[12:13]\n\t"
            "v_pk_fma_f32 v[14:15], v[224:225], v[6:7], v[14:15]\n\t"
            "ds_read_b128 v[4:7], v33 offset:160\n\t"
            // m=9 (B): kp 18,19
            "s_waitcnt lgkmcnt(1)\n\t"
            "v_pk_fma_f32 v[8:9],   v[76:77],   v[16:17], v[8:9]\n\t"
            "v_pk_fma_f32 v[10:11], v[126:127], v[16:17], v[10:11]\n\t"
            "v_pk_fma_f32 v[12:13], v[176:177], v[16:17], v[12:13]\n\t"
            "v_pk_fma_f32 v[14:15], v[226:227], v[16:17], v[14:15]\n\t"
            "v_pk_fma_f32 v[8:9],   v[78:79],   v[18:19], v[8:9]\n\t"
            "v_pk_fma_f32 v[10:11], v[128:129], v[18:19], v[10:11]\n\t"
            "v_pk_fma_f32 v[12:13], v[178:179], v[18:19], v[12:13]\n\t"
            "v_pk_fma_f32 v[14:15], v[228:229], v[18:19], v[14:15]\n\t"
            "ds_read_b128 v[16:19], v33 offset:176\n\t"
            // m=10 (A): kp 20,21
            "s_waitcnt lgkmcnt(1)\n\t"
            "v_pk_fma_f32 v[8:9],   v[80:81],   v[4:5], v[8:9]\n\t"
            "v_pk_fma_f32 v[10:11], v[130:131], v[4:5], v[10:11]\n\t"
            "v_pk_fma_f32 v[12:13], v[180:181], v[4:5], v[12:13]\n\t"
            "v_pk_fma_f32 v[14:15], v[230:231], v[4:5], v[14:15]\n\t"
            "v_pk_fma_f32 v[8:9],   v[82:83],   v[6:7], v[8:9]\n\t"
            "v_pk_fma_f32 v[10:11], v[132:133], v[6:7], v[10:11]\n\t"
            "v_pk_fma_f32 v[12:13], v[182:183], v[6:7], v[12:13]\n\t"
            "v_pk_fma_f32 v[14:15], v[232:233], v[6:7], v[14:15]\n\t"
            "ds_read_b128 v[4:7], v33 offset:192\n\t"
            // m=11 (B): kp 22,23
            "s_waitcnt lgkmcnt(1)\n\t"
            "v_pk_fma_f32 v[8:9],   v[84:85],   v[16:17], v[8:9]\n\t"
            "v_pk_fma_f32 v[10:11], v[134:135], v[16:17], v[10:11]\n\t"
            "v_pk_fma_f32 v[12:13], v[184:185], v[16:17], v[12:13]\n\t"
            "v_pk_fma_f32 v[14:15], v[234:235], v[16:17], v[14:15]\n\t"
            "v_pk_fma_f32 v[8:9],   v[86:87],   v[18:19], v[8:9]\n\t"
            "v_pk_fma_f32 v[10:11], v[136:137], v[18:19], v[10:11]\n\t"
            "v_pk_fma_f32 v[12:13], v[186:187], v[18:19], v[12:13]\n\t"
            "v_pk_fma_f32 v[14:15], v[236:237], v[18:19], v[14:15]\n\t"
            // m=12 (A): kp 24 (h[48],h[49] in v[4:5]; v[6:7] = pad, unused)
            "s_waitcnt lgkmcnt(0)\n\t"
            "v_pk_fma_f32 v[8:9],   v[88:89],   v[4:5], v[8:9]\n\t"
            "v_pk_fma_f32 v[10:11], v[138:139], v[4:5], v[10:11]\n\t"
            "v_pk_fma_f32 v[12:13], v[188:189], v[4:5], v[12:13]\n\t"
            "v_pk_fma_f32 v[14:15], v[238:239], v[4:5], v[14:15]\n\t"
            // ---- fold halves, activations (exp2-based, rcp), c/h update ----
            "v_add_f32 v8,  v8,  v9\n\t"
            "v_add_f32 v10, v10, v11\n\t"
            "v_add_f32 v12, v12, v13\n\t"
            "v_add_f32 v14, v14, v15\n\t"
            "v_mul_f32 v20, 0xbfb8aa3b, v8\n\t"    // -log2e * ai
            "v_mul_f32 v21, 0xbfb8aa3b, v10\n\t"
            "v_mul_f32 v22, 0x4038aa3b, v12\n\t"   // 2*log2e * ag
            "v_mul_f32 v23, 0xbfb8aa3b, v14\n\t"
            "v_exp_f32 v20, v20\n\t"
            "v_exp_f32 v21, v21\n\t"
            "v_exp_f32 v22, v22\n\t"
            "v_exp_f32 v23, v23\n\t"
            "v_add_f32 v20, 1.0, v20\n\t"
            "v_add_f32 v21, 1.0, v21\n\t"
            "v_add_f32 v22, 1.0, v22\n\t"
            "v_add_f32 v23, 1.0, v23\n\t"
            "v_rcp_f32 v20, v20\n\t"               // gi
            "v_rcp_f32 v21, v21\n\t"               // gf
            "v_rcp_f32 v22, v22\n\t"               // 1/(e^2g+1)
            "v_rcp_f32 v23, v23\n\t"               // go
            "s_nop 1\n\t"
            "v_fma_f32 v22, -2.0, v22, 1.0\n\t"    // gg = tanh
            "v_mul_f32 v24, v20, v22\n\t"          // gi*gg
            "v_fma_f32 v30, v21, v30, v24\n\t"     // c = gf*c + gi*gg
            "v_mul_f32 v25, 0x4038aa3b, v30\n\t"
            "v_exp_f32 v25, v25\n\t"
            "s_nop 1\n\t"
            "v_add_f32 v25, 1.0, v25\n\t"
            "v_rcp_f32 v25, v25\n\t"
            "s_nop 1\n\t"
            "v_fma_f32 v25, -2.0, v25, 1.0\n\t"    // tanh(c)
            "v_mul_f32 v31, v23, v25\n\t"          // hn = go*tanh(c)
            "ds_write_b32 v34, v31\n\t"
            "s_sub_u32 s20, s20, 1\n\t"
            "s_cmp_lg_u32 s20, 0\n\t"
            "s_cbranch_scc1 1b\n\t"
            "v_mov_b32 %[hn], v31\n\t"
            : [hn] "=v"(hn)
            : [wb] "s"(W_hh),
              [woi] "v"(woi), [wof] "v"(wof), [wog] "v"(wog), [woo] "v"(woo),
              [xwi] "v"(xii), [xwf] "v"(xif), [xwg] "v"(xig), [xwo] "v"(xio),
              [bi] "v"(bi), [bf] "v"(bf), [bg] "v"(bg), [bo] "v"(bo),
              [xa0] "v"(xa0), [hb] "v"(hb_off), [hw] "v"(hw_off)
            : "memory", "scc", "s20",
              "v4","v5","v6","v7","v8","v9","v10","v11","v12","v13","v14","v15",
              "v16","v17","v18","v19","v20","v21","v22","v23","v24","v25","v26",
              "v27","v28","v29","v30","v31","v32","v33","v34","v35",
              "v40","v41","v42","v43","v44","v45","v46","v47","v48","v49",
              "v50","v51","v52","v53","v54","v55","v56","v57","v58","v59",
              "v60","v61","v62","v63","v64","v65","v66","v67","v68","v69",
              "v70","v71","v72","v73","v74","v75","v76","v77","v78","v79",
              "v80","v81","v82","v83","v84","v85","v86","v87","v88","v89",
              "v90","v91","v92","v93","v94","v95","v96","v97","v98","v99",
              "v100","v101","v102","v103","v104","v105","v106","v107","v108","v109",
              "v110","v111","v112","v113","v114","v115","v116","v117","v118","v119",
              "v120","v121","v122","v123","v124","v125","v126","v127","v128","v129",
              "v130","v131","v132","v133","v134","v135","v136","v137","v138","v139",
              "v140","v141","v142","v143","v144","v145","v146","v147","v148","v149",
              "v150","v151","v152","v153","v154","v155","v156","v157","v158","v159",
              "v160","v161","v162","v163","v164","v165","v166","v167","v168","v169",
              "v170","v171","v172","v173","v174","v175","v176","v177","v178","v179",
              "v180","v181","v182","v183","v184","v185","v186","v187","v188","v189",
              "v190","v191","v192","v193","v194","v195","v196","v197","v198","v199",
              "v200","v201","v202","v203","v204","v205","v206","v207","v208","v209",
              "v210","v211","v212","v213","v214","v215","v216","v217","v218","v219",
              "v220","v221","v222","v223","v224","v225","v226","v227","v228","v229",
              "v230","v231","v232","v233","v234","v235","v236","v237","v238","v239");

        // ---- FC head: pred = h . W_fc + b_fc (full-wave shuffle reduce) ----
        float v = (j < HSZ) ? hn * wfc : 0.f;
        #pragma unroll
        for (int off = 32; off >= 1; off >>= 1)
            v += __shfl_down(v, off, 64);
        if (j == 0) {
            const float pr = v + bfc;
            xbuf[TLEN + p] = pr;               // becomes next input
            out[b * NP + p] = pr;
        }
    }
}

extern "C" void kernel_launch(void* const* d_in, const int* in_sizes, int n_in,
                              void* d_out, int out_size, void* d_ws, size_t ws_size,
                              hipStream_t stream)
{
    const float* x    = (const float*)d_in[0];
    const float* W_ih = (const float*)d_in[1];
    const float* W_hh = (const float*)d_in[2];
    const float* b_ih = (const float*)d_in[3];
    const float* b_hh = (const float*)d_in[4];
    const float* W_fc = (const float*)d_in[5];
    const float* b_fc = (const float*)d_in[6];
    const int*   np   = (const int*)d_in[7];
    float* out = (float*)d_out;

    const int B = in_sizes[0] / TLEN;   // 1024
    rec_lstm_kernel<<<B, 64, 0, stream>>>(x, W_ih, W_hh, b_ih, b_hh,
                                          W_fc, b_fc, np, out);
}